// Round 1
// baseline (821.015 us; speedup 1.0000x reference)
//
#include <hip/hip_runtime.h>
#include <math.h>

#define EPSF 1.01e-08f

namespace {
constexpr int NB = 4;                 // batch
constexpr int HH = 252, TW = 2048;    // conv1 spatial
constexpr int C1 = 16, DD = 12, FF = 84;
constexpr int LLEN = FF * TW;         // 172032

// workspace layout (float elements)
constexpr size_t OFF_H   = 0;
constexpr size_t SZ_H    = (size_t)NB * C1 * HH * TW;       // 33,030,144
constexpr size_t SZ_QKV  = (size_t)NB * LLEN * DD;          // 8,257,536
constexpr size_t OFF_Q   = OFF_H + SZ_H;
constexpr size_t OFF_K   = OFF_Q + SZ_QKV;
constexpr size_t OFF_V   = OFF_K + SZ_QKV;
constexpr size_t OFF_SI  = OFF_V + SZ_QKV;                  // sink_in  (NB*LLEN)
constexpr size_t OFF_SA  = OFF_SI + (size_t)NB * LLEN;      // sink_alloc
constexpr size_t OFF_WP  = OFF_SA + (size_t)NB * LLEN;      // folded conv1 w (3200)
constexpr size_t OFF_B1  = OFF_WP + 3200;                   // folded conv1 b (16)
constexpr size_t OFF_WQT = OFF_B1 + 16;                     // wq transposed (1728)
constexpr size_t OFF_WKT = OFF_WQT + 1728;                  // wkv transposed (1728)
constexpr size_t FTOT    = OFF_WKT + 1728;
constexpr size_t DBYTE   = FTOT * sizeof(float);            // 8-byte aligned

// f64 accumulator slots (index into double*)
constexpr int DO_MSUM = 0;     // 4
constexpr int DO_KSUM = 4;     // 4*12
constexpr int DO_QSUM = 52;    // 4*12
constexpr int DO_SKQ  = 100;   // 4*12
constexpr int DO_SQS  = 148;   // 4*12
constexpr int DO_SE   = 196;   // 4
constexpr int DO_M    = 200;   // 4*144
constexpr int NDBL    = 776;
}

__device__ __forceinline__ float wsum(float v) {
#pragma unroll
  for (int m = 1; m < 64; m <<= 1) v += __shfl_xor(v, m, 64);
  return v;
}
__device__ __forceinline__ double wsumd(double v) {
#pragma unroll
  for (int m = 1; m < 64; m <<= 1) v += __shfl_xor(v, m, 64);
  return v;
}
__device__ __forceinline__ void atomAddD(double* p, double v) { unsafeAtomicAdd(p, v); }
__device__ __forceinline__ float sigm(float x) { return 1.f / (1.f + expf(-x)); }

// ---------------- weight prep: fold BN into conv1, transpose conv2 weights ----
__global__ void k_prep(const float* __restrict__ w_pre, const float* __restrict__ b_pre,
                       const float* __restrict__ g, const float* __restrict__ be,
                       const float* __restrict__ mean, const float* __restrict__ var,
                       const float* __restrict__ wq, const float* __restrict__ wkv,
                       float* __restrict__ ws) {
  int tid = blockIdx.x * 256 + threadIdx.x;
  int stride = gridDim.x * 256;
  if (tid < 16) {
    float sc = g[tid] / sqrtf(var[tid] + 1e-5f);
    ws[OFF_B1 + tid] = (b_pre[tid] - mean[tid]) * sc + be[tid];
  }
  for (int idx = tid; idx < 3200; idx += stride) {
    int co = idx & 15, r = idx >> 4;     // r = ci*25 + p
    int ci = r / 25, p = r % 25;
    float sc = g[co] / sqrtf(var[co] + 1e-5f);
    ws[OFF_WP + idx] = w_pre[(co * 8 + ci) * 25 + p] * sc;
  }
  for (int idx = tid; idx < 1728; idx += stride) {
    int d = idx % 12, r = idx / 12;      // r = c*9 + p
    ws[OFF_WQT + idx] = wq[d * 144 + r];
    ws[OFF_WKT + idx] = wkv[d * 144 + r];
  }
}

// ---------------- conv1 5x5 same + BN(folded) + LeakyReLU --------------------
__global__ __launch_bounds__(256) void k_conv1(const float* __restrict__ x,
                                               const float* __restrict__ wsc,
                                               float* __restrict__ h) {
  const int t = blockIdx.x * 256 + threadIdx.x;
  const int y = blockIdx.y;
  const int b = blockIdx.z;
  const float* __restrict__ wp = wsc + OFF_WP;
  const float* __restrict__ b1 = wsc + OFF_B1;
  float acc[16];
#pragma unroll
  for (int i = 0; i < 16; i++) acc[i] = 0.f;
  for (int ci = 0; ci < 8; ci++) {
    const float* xc = x + (size_t)(b * 8 + ci) * HH * TW;
#pragma unroll
    for (int kh = 0; kh < 5; kh++) {
      int yy = y + kh - 2;
      bool rok = (yy >= 0) & (yy < HH);
      const float* xr = xc + (size_t)yy * TW;
#pragma unroll
      for (int kw = 0; kw < 5; kw++) {
        int tt = t + kw - 2;
        bool ok = rok & (tt >= 0) & (tt < TW);
        float xv = ok ? xr[tt] : 0.f;
        const float* wr = wp + (ci * 25 + kh * 5 + kw) * 16;
#pragma unroll
        for (int co = 0; co < 16; co++) acc[co] = fmaf(xv, wr[co], acc[co]);
      }
    }
  }
  size_t base = ((size_t)(b * 16) * HH + y) * TW + t;
#pragma unroll
  for (int co = 0; co < 16; co++) {
    float z = acc[co] + b1[co];
    z = (z >= 0.f) ? z : 0.01f * z;
    h[base + (size_t)co * HH * TW] = z;
  }
}

// ---------------- mask_sum per batch -----------------------------------------
__global__ void k_masksum(const float* __restrict__ frame, double* __restrict__ dacc) {
  const int b = blockIdx.y;
  const float* fr = frame + (size_t)b * FF * TW;
  double s = 0.0;
  for (int i = blockIdx.x * 256 + threadIdx.x; i < FF * TW; i += gridDim.x * 256)
    s += (double)fr[i];
  s = wsumd(s);
  __shared__ double sm[4];
  int lane = threadIdx.x & 63, wid = threadIdx.x >> 6;
  if (lane == 0) sm[wid] = s;
  __syncthreads();
  if (threadIdx.x == 0) atomAddD(&dacc[DO_MSUM + b], sm[0] + sm[1] + sm[2] + sm[3]);
}

// ---------------- conv2 (Q & KV) + masknorm + projections + sigmoid ----------
__global__ __launch_bounds__(256) void k_conv2(
    const float* __restrict__ h, const float* __restrict__ frame,
    const float* __restrict__ wsc, double* __restrict__ dacc,
    const float* __restrict__ fwq, const float* __restrict__ fbq,
    const float* __restrict__ fwk, const float* __restrict__ fbk,
    const float* __restrict__ fwv, const float* __restrict__ fbv,
    const float* __restrict__ bqc, const float* __restrict__ bkvc,
    const float* __restrict__ Tp,
    float* __restrict__ qo, float* __restrict__ ko, float* __restrict__ vo) {
  const int t = blockIdx.x * 256 + threadIdx.x;
  const int f = blockIdx.y;
  const int b = blockIdx.z;
  const float* __restrict__ wqt = wsc + OFF_WQT;
  const float* __restrict__ wkt = wsc + OFF_WKT;
  float aq[12], akv[12];
#pragma unroll
  for (int d = 0; d < 12; d++) { aq[d] = bqc[d]; akv[d] = bkvc[d]; }
  for (int c = 0; c < 16; c++) {
    const float* hr = h + ((size_t)(b * 16 + c) * HH + 3 * f) * TW;
#pragma unroll
    for (int kh = 0; kh < 3; kh++) {
#pragma unroll
      for (int kw = 0; kw < 3; kw++) {
        int tt = t + kw - 1;
        bool ok = (tt >= 0) & (tt < TW);
        float xv = ok ? hr[kh * TW + tt] : 0.f;
        const float* w1 = wqt + (c * 9 + kh * 3 + kw) * 12;
        const float* w2 = wkt + (c * 9 + kh * 3 + kw) * 12;
#pragma unroll
        for (int d = 0; d < 12; d++) {
          aq[d] = fmaf(xv, w1[d], aq[d]);
          akv[d] = fmaf(xv, w2[d], akv[d]);
        }
      }
    }
  }
  // masknorm (mask_norm=True) * T
  float ss = EPSF;
#pragma unroll
  for (int d = 0; d < 12; d++) ss = fmaf(akv[d], akv[d], ss);
  float amp = sqrtf(ss);
  float mk = frame[((size_t)b * FF + f) * TW + t];
  float msum = (float)dacc[DO_MSUM + b];
  float sc = mk * Tp[0] / (amp * msum);
  float kvn[12];
#pragma unroll
  for (int d = 0; d < 12; d++) kvn[d] = akv[d] * sc;
  // projections + sigmoid(q,k)
  float qv[12], kk[12], vv[12];
#pragma unroll
  for (int d = 0; d < 12; d++) {
    float s1 = fbq[d], s2 = fbk[d], s3 = fbv[d];
#pragma unroll
    for (int e = 0; e < 12; e++) {
      s1 = fmaf(aq[e], fwq[e * 12 + d], s1);
      s2 = fmaf(kvn[e], fwk[e * 12 + d], s2);
      s3 = fmaf(kvn[e], fwv[e * 12 + d], s3);
    }
    qv[d] = sigm(s1);
    kk[d] = sigm(s2);
    vv[d] = s3;
  }
  size_t l = (size_t)f * TW + t;
  size_t o = ((size_t)b * LLEN + l) * 12;
#pragma unroll
  for (int d = 0; d < 12; d++) { qo[o + d] = qv[d]; ko[o + d] = kk[d]; vo[o + d] = vv[d]; }
  // block-reduce qsum/ksum -> f64 atomics
  float part[24];
#pragma unroll
  for (int d = 0; d < 12; d++) { part[d] = qv[d]; part[12 + d] = kk[d]; }
  __shared__ float red[4 * 24];
  int lane = threadIdx.x & 63, wid = threadIdx.x >> 6;
#pragma unroll
  for (int j = 0; j < 24; j++) {
    float s = wsum(part[j]);
    if (lane == 0) red[wid * 24 + j] = s;
  }
  __syncthreads();
  if (threadIdx.x < 24) {
    float tot = red[threadIdx.x] + red[24 + threadIdx.x] + red[48 + threadIdx.x] + red[72 + threadIdx.x];
    int idx = (threadIdx.x < 12) ? (DO_QSUM + b * 12 + threadIdx.x)
                                 : (DO_KSUM + b * 12 + (threadIdx.x - 12));
    atomAddD(&dacc[idx], (double)tot);
  }
}

// ---------------- sink_in / src_out + skq,sqs reductions ---------------------
__global__ __launch_bounds__(256) void k_sink(const float* __restrict__ q,
                                              const float* __restrict__ k,
                                              float* __restrict__ sink_in,
                                              double* __restrict__ dacc) {
  const int b = blockIdx.y;
  const int tid0 = blockIdx.x * 256 + threadIdx.x;  // [0, 21504)
  float ksE[12], qsE[12];
#pragma unroll
  for (int d = 0; d < 12; d++) {
    ksE[d] = (float)(dacc[DO_KSUM + b * 12 + d] + (double)EPSF);
    qsE[d] = (float)(dacc[DO_QSUM + b * 12 + d] + (double)EPSF);
  }
  float askq[12], asqs[12];
#pragma unroll
  for (int d = 0; d < 12; d++) { askq[d] = 0.f; asqs[d] = 0.f; }
  for (int it = 0; it < 8; it++) {
    size_t l = (size_t)it * 21504 + tid0;
    const float* qp = q + ((size_t)b * LLEN + l) * 12;
    const float* kp = k + ((size_t)b * LLEN + l) * 12;
    float qv[12], kv[12];
#pragma unroll
    for (int d = 0; d < 12; d++) { qv[d] = qp[d]; kv[d] = kp[d]; }
    float s1 = 0.f, s2 = 0.f;
#pragma unroll
    for (int d = 0; d < 12; d++) {
      s1 = fmaf(qv[d] + EPSF, ksE[d], s1);
      s2 = fmaf(kv[d] + EPSF, qsE[d], s2);
    }
    float si = 1.f / s1;
    float so = 1.f / s2;
    sink_in[(size_t)b * LLEN + l] = si;
#pragma unroll
    for (int d = 0; d < 12; d++) {
      askq[d] = fmaf(kv[d], so, askq[d]);
      asqs[d] = fmaf(qv[d], si, asqs[d]);
    }
  }
  float part[24];
#pragma unroll
  for (int d = 0; d < 12; d++) { part[d] = askq[d]; part[12 + d] = asqs[d]; }
  __shared__ float red[4 * 24];
  int lane = threadIdx.x & 63, wid = threadIdx.x >> 6;
#pragma unroll
  for (int j = 0; j < 24; j++) {
    float s = wsum(part[j]);
    if (lane == 0) red[wid * 24 + j] = s;
  }
  __syncthreads();
  if (threadIdx.x < 24) {
    float tot = red[threadIdx.x] + red[24 + threadIdx.x] + red[48 + threadIdx.x] + red[72 + threadIdx.x];
    int idx = (threadIdx.x < 12) ? (DO_SKQ + b * 12 + threadIdx.x)
                                 : (DO_SQS + b * 12 + (threadIdx.x - 12));
    atomAddD(&dacc[idx], (double)tot);
  }
}

// ---------------- sink_alloc + exp(cons_src) + kv-matrix + sumexp ------------
__global__ __launch_bounds__(256) void k_flow(const float* __restrict__ q,
                                              const float* __restrict__ k,
                                              const float* __restrict__ v,
                                              float* __restrict__ sink_alloc,
                                              double* __restrict__ dacc) {
  const int b = blockIdx.y;
  const int tid0 = blockIdx.x * 256 + threadIdx.x;
  float skqE[12], sqsE[12];
#pragma unroll
  for (int d = 0; d < 12; d++) {
    skqE[d] = (float)(dacc[DO_SKQ + b * 12 + d] + (double)EPSF);
    sqsE[d] = (float)(dacc[DO_SQS + b * 12 + d] + (double)EPSF);
  }
  float acc[144];
#pragma unroll
  for (int j = 0; j < 144; j++) acc[j] = 0.f;
  double se = 0.0;
  for (int it = 0; it < 8; it++) {
    size_t l = (size_t)it * 21504 + tid0;
    size_t o = ((size_t)b * LLEN + l) * 12;
    float qv[12], kv[12], vv[12];
#pragma unroll
    for (int d = 0; d < 12; d++) { qv[d] = q[o + d]; kv[d] = k[o + d]; vv[d] = v[o + d]; }
    float c1 = 0.f, c2 = 0.f;
#pragma unroll
    for (int d = 0; d < 12; d++) {
      c1 = fmaf(qv[d] + EPSF, skqE[d], c1);
      c2 = fmaf(kv[d] + EPSF, sqsE[d], c2);
    }
    sink_alloc[(size_t)b * LLEN + l] = sigm(c1);
    float e = expf(c2);
    se += (double)e;
#pragma unroll
    for (int d = 0; d < 12; d++) {
      float ke = kv[d] * e;
#pragma unroll
      for (int m = 0; m < 12; m++) acc[d * 12 + m] = fmaf(ke, vv[m], acc[d * 12 + m]);
    }
  }
  __shared__ float red[4 * 144];
  __shared__ double seds[4];
  int lane = threadIdx.x & 63, wid = threadIdx.x >> 6;
#pragma unroll
  for (int j = 0; j < 144; j++) {
    float s = wsum(acc[j]);
    if (lane == 0) red[wid * 144 + j] = s;
  }
  double sew = wsumd(se);
  if (lane == 0) seds[wid] = sew;
  __syncthreads();
  if (threadIdx.x < 144) {
    float tot = red[threadIdx.x] + red[144 + threadIdx.x] + red[288 + threadIdx.x] + red[432 + threadIdx.x];
    atomAddD(&dacc[DO_M + b * 144 + threadIdx.x], (double)tot);
  }
  if (threadIdx.x == 192) atomAddD(&dacc[DO_SE + b], seds[0] + seds[1] + seds[2] + seds[3]);
}

// ---------------- final: out = (q@kv)*sink_in*sink_alloc @ Wo + bo -----------
__global__ __launch_bounds__(256) void k_out(const float* __restrict__ q,
                                             const float* __restrict__ sink_in,
                                             const float* __restrict__ sink_alloc,
                                             const double* __restrict__ dacc,
                                             const float* __restrict__ wo,
                                             const float* __restrict__ bo,
                                             float* __restrict__ out) {
  const int t = blockIdx.x * 256 + threadIdx.x;
  const int f = blockIdx.y;
  const int b = blockIdx.z;
  __shared__ float kvf[144];
  if (threadIdx.x < 144) {
    double fac = (double)LLEN / dacc[DO_SE + b];
    kvf[threadIdx.x] = (float)(dacc[DO_M + b * 144 + threadIdx.x] * fac);
  }
  __syncthreads();
  size_t l = (size_t)f * TW + t;
  const float* qp = q + ((size_t)b * LLEN + l) * 12;
  float qv[12];
#pragma unroll
  for (int d = 0; d < 12; d++) qv[d] = qp[d];
  float s = sink_in[(size_t)b * LLEN + l] * sink_alloc[(size_t)b * LLEN + l];
  float o[12];
#pragma unroll
  for (int m = 0; m < 12; m++) {
    float a = 0.f;
#pragma unroll
    for (int d = 0; d < 12; d++) a = fmaf(qv[d], kvf[d * 12 + m], a);
    o[m] = a * s;
  }
#pragma unroll
  for (int m2 = 0; m2 < 12; m2++) {
    float a = bo[m2];
#pragma unroll
    for (int m = 0; m < 12; m++) a = fmaf(o[m], wo[m * 12 + m2], a);
    out[((size_t)b * 12 + m2) * LLEN + l] = a;
  }
}

extern "C" void kernel_launch(void* const* d_in, const int* in_sizes, int n_in,
                              void* d_out, int out_size, void* d_ws, size_t ws_size,
                              hipStream_t stream) {
  (void)in_sizes; (void)n_in; (void)out_size; (void)ws_size;
  const float* x     = (const float*)d_in[0];
  const float* frame = (const float*)d_in[1];
  const float* w_pre = (const float*)d_in[2];
  const float* b_pre = (const float*)d_in[3];
  const float* gam   = (const float*)d_in[4];
  const float* bet   = (const float*)d_in[5];
  const float* mean  = (const float*)d_in[6];
  const float* var   = (const float*)d_in[7];
  const float* Tp    = (const float*)d_in[8];
  const float* wq_c  = (const float*)d_in[9];
  const float* bq_c  = (const float*)d_in[10];
  const float* wkv_c = (const float*)d_in[11];
  const float* bkv_c = (const float*)d_in[12];
  const float* fa_wq = (const float*)d_in[13];
  const float* fa_bq = (const float*)d_in[14];
  const float* fa_wk = (const float*)d_in[15];
  const float* fa_bk = (const float*)d_in[16];
  const float* fa_wv = (const float*)d_in[17];
  const float* fa_bv = (const float*)d_in[18];
  const float* fa_wo = (const float*)d_in[19];
  const float* fa_bo = (const float*)d_in[20];

  float* ws = (float*)d_ws;
  double* dacc = (double*)((char*)d_ws + DBYTE);
  float* out = (float*)d_out;

  hipMemsetAsync(dacc, 0, NDBL * sizeof(double), stream);
  k_prep<<<dim3(16), 256, 0, stream>>>(w_pre, b_pre, gam, bet, mean, var, wq_c, wkv_c, ws);
  k_masksum<<<dim3(64, 4), 256, 0, stream>>>(frame, dacc);
  k_conv1<<<dim3(8, 252, 4), 256, 0, stream>>>(x, ws, ws + OFF_H);
  k_conv2<<<dim3(8, 84, 4), 256, 0, stream>>>(ws + OFF_H, frame, ws, dacc,
      fa_wq, fa_bq, fa_wk, fa_bk, fa_wv, fa_bv, bq_c, bkv_c, Tp,
      ws + OFF_Q, ws + OFF_K, ws + OFF_V);
  k_sink<<<dim3(84, 4), 256, 0, stream>>>(ws + OFF_Q, ws + OFF_K, ws + OFF_SI, dacc);
  k_flow<<<dim3(84, 4), 256, 0, stream>>>(ws + OFF_Q, ws + OFF_K, ws + OFF_V, ws + OFF_SA, dacc);
  k_out<<<dim3(8, 84, 4), 256, 0, stream>>>(ws + OFF_Q, ws + OFF_SI, ws + OFF_SA, dacc,
      fa_wo, fa_bo, out);
}